// Round 1
// baseline (1218.535 us; speedup 1.0000x reference)
//
#include <hip/hip_runtime.h>
#include <hip/hip_bf16.h>

#define BM 64
#define BN 64
#define BK 16

// C[m][n] = (relu?)(sum_k A[m*lda+k] * B[n*ldb+k] + bias[n])
template<bool RELU, bool BIAS>
__global__ __launch_bounds__(256)
void gemm_abt(const float* __restrict__ A, int lda,
              const float* __restrict__ B, int ldb,
              const float* __restrict__ bias,
              float* __restrict__ C, int ldc,
              int M, int N, int K)
{
    __shared__ float As[BK][BM + 4];  // [k][m], row stride 68 floats (272B, 16B-aligned)
    __shared__ float Bs[BK][BN + 4];
    const int bm = blockIdx.y * BM, bn = blockIdx.x * BN;
    const int tid = threadIdx.x;
    const int tx = tid & 15, ty = tid >> 4;   // 16x16 thread grid, 4x4 microtile
    float acc[4][4] = {};

    for (int k0 = 0; k0 < K; k0 += BK) {
        #pragma unroll
        for (int l = tid; l < BM * BK; l += 256) {
            const int kk = l & (BK - 1);
            const int m  = l >> 4;
            const int gk = k0 + kk;
            const int gm = bm + m;
            const int gn = bn + m;
            As[kk][m] = (gm < M && gk < K) ? A[(size_t)gm * lda + gk] : 0.f;
            Bs[kk][m] = (gn < N && gk < K) ? B[(size_t)gn * ldb + gk] : 0.f;
        }
        __syncthreads();
        #pragma unroll
        for (int kk = 0; kk < BK; ++kk) {
            const float4 av = *(const float4*)&As[kk][ty * 4];
            const float4 bv = *(const float4*)&Bs[kk][tx * 4];
            const float a[4] = {av.x, av.y, av.z, av.w};
            const float b[4] = {bv.x, bv.y, bv.z, bv.w};
            #pragma unroll
            for (int i = 0; i < 4; ++i)
                #pragma unroll
                for (int j = 0; j < 4; ++j)
                    acc[i][j] += a[i] * b[j];
        }
        __syncthreads();
    }

    float bb[4];
    #pragma unroll
    for (int j = 0; j < 4; ++j) {
        const int gn = bn + tx * 4 + j;
        bb[j] = (BIAS && gn < N) ? bias[gn] : 0.f;
    }
    #pragma unroll
    for (int i = 0; i < 4; ++i) {
        const int gm = bm + ty * 4 + i;
        if (gm >= M) continue;
        #pragma unroll
        for (int j = 0; j < 4; ++j) {
            const int gn = bn + tx * 4 + j;
            if (gn >= N) continue;
            float v = acc[i][j] + bb[j];
            if (RELU) v = fmaxf(v, 0.f);
            C[(size_t)gm * ldc + gn] = v;
        }
    }
}

// One block per (b,s). Stages hx[b,s,:]+b3 and W4 in LDS, loops over n.
__global__ __launch_bounds__(256)
void score_loss(const float* __restrict__ hx,   // [B*S][H]
                const float* __restrict__ ha,   // [B*N][H]
                const float* __restrict__ b3,   // [H]
                const float* __restrict__ W4,   // [H]
                const float* __restrict__ b4,   // [1]
                const int* __restrict__ xl,     // [B*S]
                const int* __restrict__ al,     // [B*N]
                float* __restrict__ out,        // [1]
                int B, int S, int N, int H)
{
    __shared__ float hxs[900];
    __shared__ float w4s[900];
    __shared__ float red[4];
    const int bs = blockIdx.x;          // 0..B*S-1
    const int b = bs / S;
    const int tid = threadIdx.x;

    for (int h = tid; h < H; h += 256) {
        hxs[h] = hx[(size_t)bs * H + h] + b3[h];
        w4s[h] = W4[h];
    }
    __syncthreads();

    const float b4v = b4[0];
    const int xlab = xl[bs];
    float lossacc = 0.f;

    for (int n = 0; n < N; ++n) {
        const float* __restrict__ har = ha + (size_t)(b * N + n) * H;
        float p = 0.f;
        for (int h = tid; h < H; h += 256)
            p += fmaxf(hxs[h] + har[h], 0.f) * w4s[h];
        // 64-lane wave reduce
        #pragma unroll
        for (int off = 32; off > 0; off >>= 1)
            p += __shfl_down(p, off);
        const int lane = tid & 63, wv = tid >> 6;
        if (lane == 0) red[wv] = p;
        __syncthreads();
        if (tid == 0) {
            const float z = red[0] + red[1] + red[2] + red[3] + b4v;
            const float sc = 1.f / (1.f + expf(-z));
            const float lab = (xlab == al[b * N + n]) ? 1.f : 0.f;
            const float d = lab - sc;
            lossacc += d * d;
        }
        __syncthreads();
    }
    if (tid == 0) atomicAdd(out, lossacc / (float)(B * S));
}

extern "C" void kernel_launch(void* const* d_in, const int* in_sizes, int n_in,
                              void* d_out, int out_size, void* d_ws, size_t ws_size,
                              hipStream_t stream)
{
    const float* x   = (const float*)d_in[0];
    const int*   xl  = (const int*)  d_in[1];
    const float* att = (const float*)d_in[2];
    const int*   al  = (const int*)  d_in[3];
    const float* W1  = (const float*)d_in[4];
    const float* b1  = (const float*)d_in[5];
    const float* W2  = (const float*)d_in[6];
    const float* b2  = (const float*)d_in[7];
    const float* W3  = (const float*)d_in[8];
    const float* b3  = (const float*)d_in[9];
    const float* W4  = (const float*)d_in[10];
    const float* b4  = (const float*)d_in[11];
    float* out = (float*)d_out;
    float* ws  = (float*)d_ws;

    const int B = 4, S = 128, N = 50, C = 4096, H = 900, AR = 312;

    float* h1   = ws;                   // 200*900
    float* attf = h1 + B * N * H;       // 200*4096
    float* hx   = attf + B * N * C;     // 512*900
    float* ha   = hx + B * S * H;       // 200*900

    hipMemsetAsync(d_out, 0, sizeof(float), stream);

    const dim3 blk(256);

    // G1: h1 = relu(att @ W1^T + b1)   [200 x 900], K=312
    gemm_abt<true, true><<<dim3((H + BN - 1) / BN, (B * N + BM - 1) / BM), blk, 0, stream>>>(
        att, AR, W1, AR, b1, h1, H, B * N, H, AR);

    // G2: att_f = relu(h1 @ W2^T + b2) [200 x 4096], K=900
    gemm_abt<true, true><<<dim3((C + BN - 1) / BN, (B * N + BM - 1) / BM), blk, 0, stream>>>(
        h1, H, W2, H, b2, attf, C, B * N, C, H);

    // G3: hx = x @ W3x^T               [512 x 900], K=4096
    gemm_abt<false, false><<<dim3((H + BN - 1) / BN, (B * S + BM - 1) / BM), blk, 0, stream>>>(
        x, C, W3, 2 * C, nullptr, hx, H, B * S, H, C);

    // G4: ha = att_f @ W3a^T           [200 x 900], K=4096
    gemm_abt<false, false><<<dim3((H + BN - 1) / BN, (B * N + BM - 1) / BM), blk, 0, stream>>>(
        attf, C, W3 + C, 2 * C, nullptr, ha, H, B * N, H, C);

    // Score + loss
    score_loss<<<dim3(B * S), blk, 0, stream>>>(hx, ha, b3, W4, b4, xl, al, out, B, S, N, H);
}

// Round 2
// 166.676 us; speedup vs baseline: 7.3108x; 7.3108x over previous
//
#include <hip/hip_runtime.h>
#include <hip/hip_bf16.h>

typedef __attribute__((ext_vector_type(8))) short bf16x8;
typedef __attribute__((ext_vector_type(4))) float f32x4;
typedef __attribute__((ext_vector_type(8))) unsigned short u16x8;

__device__ __forceinline__ void gload16(const void* g, void* l) {
    __builtin_amdgcn_global_load_lds((const __attribute__((address_space(1))) void*)g,
                                     (__attribute__((address_space(3))) void*)l, 16, 0, 0);
}

// ---------------------------------------------------------------------------
// padconv: fp32 [M][src_ld] (starting at col0) -> bf16 [Mp][Kp], zero-padded.
// Each thread produces 8 consecutive bf16 (one 16B store). Kp % 8 == 0.
// ---------------------------------------------------------------------------
__global__ __launch_bounds__(256)
void padconv(const float* __restrict__ src, int src_ld, int col0, int M, int K,
             unsigned short* __restrict__ dst, int Kp, int Mp)
{
    const int idx = blockIdx.x * 256 + threadIdx.x;
    const int kp8 = Kp >> 3;
    if (idx >= Mp * kp8) return;
    const int m = idx / kp8;
    const int kc = (idx - m * kp8) << 3;
    u16x8 v;
    #pragma unroll
    for (int j = 0; j < 8; ++j) {
        float f = 0.f;
        const int k = kc + j;
        if (m < M && k < K) f = src[(size_t)m * src_ld + col0 + k];
        __hip_bfloat16 h = __float2bfloat16(f);
        v[j] = *(unsigned short*)&h;
    }
    *(u16x8*)(dst + (size_t)m * Kp + kc) = v;
}

// ---------------------------------------------------------------------------
// MFMA GEMM: C[m][n] = act( sum_k A[m][k]*B[n][k] + bias[n] )
// A: bf16 [Mpad][Kp], B: bf16 [Npad][Kp], Kp % 64 == 0, tile 64x64, 4 waves.
// BF16OUT: store bf16 to padded [*, ldc] buffer, zeroing rows >= Mtrue.
// else:    store fp32 partial slab at C + blockIdx.z*Mtrue*ldc, guards m<Mtrue,n<Ntrue.
// Staging: global_load_lds w=16, linear LDS dest, XOR-swizzled global source;
// ds_read applies the same XOR (rule #21 both-sides).
// ---------------------------------------------------------------------------
template<bool RELU, bool BIAS, bool BF16OUT>
__global__ __launch_bounds__(256)
void gemm_mfma(const unsigned short* __restrict__ A,
               const unsigned short* __restrict__ B,
               const float* __restrict__ bias,
               void* __restrict__ Cout, int ldc,
               int Mtrue, int Ntrue, int Kp, int Kc)
{
    __shared__ short As[64 * 64];
    __shared__ short Bs[64 * 64];
    const int bm = blockIdx.y * 64, bn = blockIdx.x * 64;
    const int tid = threadIdx.x;
    const int w = tid >> 6, l = tid & 63;
    const int wm = w >> 1, wn = w & 1;
    const int k_begin = blockIdx.z * Kc;
    const int k_end   = (k_begin + Kc < Kp) ? k_begin + Kc : Kp;

    // staging geometry (per wave, 2 calls per matrix): call c covers rows c*32+w*8 .. +8
    const int sr0 = w * 8 + (l >> 3);        // row within 32-row half (before +c*32)
    const int scb = (l & 7) * 16;            // byte col within 128B row

    f32x4 acc[2][2];
    #pragma unroll
    for (int i = 0; i < 2; ++i)
        #pragma unroll
        for (int j = 0; j < 2; ++j)
            acc[i][j] = (f32x4){0.f, 0.f, 0.f, 0.f};

    for (int k0 = k_begin; k0 < k_end; k0 += 64) {
        #pragma unroll
        for (int c = 0; c < 2; ++c) {
            const int r = c * 32 + sr0;
            const int cbs = scb ^ ((r & 7) << 4);   // pre-swizzled source byte col
            const char* ga = (const char*)(A + (size_t)(bm + r) * Kp + k0) + cbs;
            const char* gb = (const char*)(B + (size_t)(bn + r) * Kp + k0) + cbs;
            char* la = (char*)As + (size_t)(c * 32 + w * 8) * 128;  // wave-uniform
            char* lb = (char*)Bs + (size_t)(c * 32 + w * 8) * 128;
            gload16(ga, la);
            gload16(gb, lb);
        }
        asm volatile("s_waitcnt vmcnt(0)");
        __syncthreads();

        #pragma unroll
        for (int ks = 0; ks < 64; ks += 32) {
            bf16x8 a[2], b[2];
            const int kb = ks * 2 + (l >> 4) * 16;   // byte col of this lane's 8 elems
            #pragma unroll
            for (int i = 0; i < 2; ++i) {
                const int ra = wm * 32 + i * 16 + (l & 15);
                a[i] = *(const bf16x8*)((const char*)As + ra * 128 + (kb ^ ((ra & 7) << 4)));
                const int rb = wn * 32 + i * 16 + (l & 15);
                b[i] = *(const bf16x8*)((const char*)Bs + rb * 128 + (kb ^ ((rb & 7) << 4)));
            }
            #pragma unroll
            for (int i = 0; i < 2; ++i)
                #pragma unroll
                for (int j = 0; j < 2; ++j)
                    acc[i][j] = __builtin_amdgcn_mfma_f32_16x16x32_bf16(a[i], b[j], acc[i][j], 0, 0, 0);
        }
        __syncthreads();
    }

    // epilogue: C/D layout col=lane&15, row=(lane>>4)*4+reg
    #pragma unroll
    for (int i = 0; i < 2; ++i) {
        #pragma unroll
        for (int j = 0; j < 2; ++j) {
            const int col = bn + wn * 32 + j * 16 + (l & 15);
            float bv = 0.f;
            if (BIAS && col < Ntrue) bv = bias[col];
            #pragma unroll
            for (int q = 0; q < 4; ++q) {
                const int row = bm + wm * 32 + i * 16 + (l >> 4) * 4 + q;
                float v = acc[i][j][q] + bv;
                if (RELU) v = fmaxf(v, 0.f);
                if (BF16OUT) {
                    if (row >= Mtrue) v = 0.f;
                    __hip_bfloat16 h = __float2bfloat16(v);
                    ((unsigned short*)Cout)[(size_t)row * ldc + col] = *(unsigned short*)&h;
                } else {
                    if (row < Mtrue && col < Ntrue) {
                        float* Cf = (float*)Cout + (size_t)blockIdx.z * Mtrue * ldc;
                        Cf[(size_t)row * ldc + col] = v;
                    }
                }
            }
        }
    }
}

// o[i] = sum over nslab slabs of p[slab*L + i], float4-vectorized (L % 4 == 0)
__global__ __launch_bounds__(256)
void reduceN(const float* __restrict__ p, float* __restrict__ o, int L, int nslab)
{
    const int i = (blockIdx.x * 256 + threadIdx.x) * 4;
    if (i >= L) return;
    float4 r = *(const float4*)(p + i);
    for (int s = 1; s < nslab; ++s) {
        const float4 t = *(const float4*)(p + (size_t)s * L + i);
        r.x += t.x; r.y += t.y; r.z += t.z; r.w += t.w;
    }
    *(float4*)(o + i) = r;
}

// ---------------------------------------------------------------------------
// score/loss: one block per (b,s); wave wv handles n = wv, wv+4, ...
// ---------------------------------------------------------------------------
__global__ __launch_bounds__(256)
void score_loss(const float* __restrict__ hx,   // [B*S][H]
                const float* __restrict__ ha,   // [B*N][H]
                const float* __restrict__ b3,
                const float* __restrict__ W4,
                const float* __restrict__ b4,
                const int* __restrict__ xl,
                const int* __restrict__ al,
                float* __restrict__ out,
                int B, int S, int N, int H)
{
    __shared__ float hxs[900];
    __shared__ float w4s[900];
    __shared__ float wloss[4];
    const int bs = blockIdx.x;
    const int b = bs / S;
    const int tid = threadIdx.x;

    for (int h = tid; h < H; h += 256) {
        hxs[h] = hx[(size_t)bs * H + h] + b3[h];
        w4s[h] = W4[h];
    }
    __syncthreads();

    const int wv = tid >> 6, l = tid & 63;
    const float b4v = b4[0];
    const int xlab = xl[bs];
    float lacc = 0.f;

    for (int n = wv; n < N; n += 4) {
        const float* __restrict__ har = ha + (size_t)(b * N + n) * H;
        float p = 0.f;
        for (int h = l; h < H; h += 64)
            p += fmaxf(hxs[h] + har[h], 0.f) * w4s[h];
        #pragma unroll
        for (int off = 32; off > 0; off >>= 1)
            p += __shfl_down(p, off);
        if (l == 0) {
            const float z = p + b4v;
            const float sc = 1.f / (1.f + expf(-z));
            const float d = ((xlab == al[b * N + n]) ? 1.f : 0.f) - sc;
            lacc += d * d;
        }
    }
    if (l == 0) wloss[wv] = lacc;
    __syncthreads();
    if (tid == 0)
        atomicAdd(out, (wloss[0] + wloss[1] + wloss[2] + wloss[3]) * (1.f / 512.f));
}

extern "C" void kernel_launch(void* const* d_in, const int* in_sizes, int n_in,
                              void* d_out, int out_size, void* d_ws, size_t ws_size,
                              hipStream_t stream)
{
    const float* x   = (const float*)d_in[0];
    const int*   xl  = (const int*)  d_in[1];
    const float* att = (const float*)d_in[2];
    const int*   al  = (const int*)  d_in[3];
    const float* W1  = (const float*)d_in[4];
    const float* b1  = (const float*)d_in[5];
    const float* W2  = (const float*)d_in[6];
    const float* b2  = (const float*)d_in[7];
    const float* W3  = (const float*)d_in[8];
    const float* b3  = (const float*)d_in[9];
    const float* W4  = (const float*)d_in[10];
    const float* b4  = (const float*)d_in[11];
    float* out = (float*)d_out;

    const int B = 4, S = 128, N = 50, C = 4096, H = 900, AR = 312;
    const int MS = B * S;           // 512
    const int MN = B * N;           // 200
    const int MNp = 256;            // padded rows for the 200-row matrices
    const int ARp = 320, Hp = 960;  // padded K dims
    const int SPLITS = 8, KC = 512; // split-K for the K=4096 GEMMs

    // ---- workspace layout (bytes, 256-aligned) ----
    char* base = (char*)d_ws;
    size_t off = 0;
    auto alloc = [&](size_t bytes) { void* r = base + off; off = (off + bytes + 255) & ~(size_t)255; return r; };
    unsigned short* x_bf   = (unsigned short*)alloc((size_t)MS * C * 2);     // [512][4096]
    unsigned short* att_bf = (unsigned short*)alloc((size_t)MNp * ARp * 2);  // [256][320]
    unsigned short* W1_bf  = (unsigned short*)alloc((size_t)Hp * ARp * 2);   // [960][320]
    unsigned short* W2_bf  = (unsigned short*)alloc((size_t)C * Hp * 2);     // [4096][960]
    unsigned short* W3x_bf = (unsigned short*)alloc((size_t)Hp * C * 2);     // [960][4096]
    unsigned short* W3a_bf = (unsigned short*)alloc((size_t)Hp * C * 2);
    unsigned short* h1_bf  = (unsigned short*)alloc((size_t)MNp * Hp * 2);   // [256][960]
    unsigned short* attf_bf= (unsigned short*)alloc((size_t)MNp * C * 2);    // [256][4096]
    float* hxp = (float*)alloc((size_t)SPLITS * MS * H * 4);                 // [8][512][900]
    float* hap = (float*)alloc((size_t)SPLITS * MN * H * 4);                 // [8][200][900]
    float* hx  = (float*)alloc((size_t)MS * H * 4);
    float* ha  = (float*)alloc((size_t)MN * H * 4);

    hipMemsetAsync(d_out, 0, sizeof(float), stream);

    const dim3 blk(256);
    auto cdiv = [](int a, int b) { return (a + b - 1) / b; };

    // ---- bf16 conversions (zero-padded) ----
    padconv<<<cdiv(MS * (C / 8), 256), blk, 0, stream>>>(x, C, 0, MS, C, x_bf, C, MS);
    padconv<<<cdiv(MNp * (ARp / 8), 256), blk, 0, stream>>>(att, AR, 0, MN, AR, att_bf, ARp, MNp);
    padconv<<<cdiv(Hp * (ARp / 8), 256), blk, 0, stream>>>(W1, AR, 0, H, AR, W1_bf, ARp, Hp);
    padconv<<<cdiv(C * (Hp / 8), 256), blk, 0, stream>>>(W2, H, 0, C, H, W2_bf, Hp, C);
    padconv<<<cdiv(Hp * (C / 8), 256), blk, 0, stream>>>(W3, 2 * C, 0, H, C, W3x_bf, C, Hp);
    padconv<<<cdiv(Hp * (C / 8), 256), blk, 0, stream>>>(W3, 2 * C, C, H, C, W3a_bf, C, Hp);

    // ---- G1: h1 = relu(att @ W1^T + b1)  [256][960] bf16, K=320 ----
    gemm_mfma<true, true, true><<<dim3(Hp / 64, MNp / 64, 1), blk, 0, stream>>>(
        att_bf, W1_bf, b1, h1_bf, Hp, MN, H, ARp, ARp);

    // ---- G2: attf = relu(h1 @ W2^T + b2) [256][4096] bf16, K=960 ----
    gemm_mfma<true, true, true><<<dim3(C / 64, MNp / 64, 1), blk, 0, stream>>>(
        h1_bf, W2_bf, b2, attf_bf, C, MN, C, Hp, Hp);

    // ---- G3: hx = x @ W3x^T  [512][900] fp32, K=4096, split-K 8 ----
    gemm_mfma<false, false, false><<<dim3(Hp / 64, MS / 64, SPLITS), blk, 0, stream>>>(
        x_bf, W3x_bf, nullptr, hxp, H, MS, H, C, KC);

    // ---- G4: ha = attf @ W3a^T [200][900] fp32, K=4096, split-K 8 ----
    gemm_mfma<false, false, false><<<dim3(Hp / 64, MNp / 64, SPLITS), blk, 0, stream>>>(
        attf_bf, W3a_bf, nullptr, hap, H, MN, H, C, KC);

    // ---- reduce split-K partials ----
    reduceN<<<cdiv(MS * H / 4, 256), blk, 0, stream>>>(hxp, hx, MS * H, SPLITS);
    reduceN<<<cdiv(MN * H / 4, 256), blk, 0, stream>>>(hap, ha, MN * H, SPLITS);

    // ---- score + loss ----
    score_loss<<<dim3(MS), blk, 0, stream>>>(hx, ha, b3, W4, b4, xl, al, out, B, S, N, H);
}

// Round 3
// 91.427 us; speedup vs baseline: 13.3279x; 1.8230x over previous
//
#include <hip/hip_runtime.h>
#include <hip/hip_bf16.h>

typedef __attribute__((ext_vector_type(8))) short bf16x8;
typedef __attribute__((ext_vector_type(4))) float f32x4;
typedef __attribute__((ext_vector_type(8))) unsigned short u16x8;

__device__ __forceinline__ void gload16(const void* g, void* l) {
    __builtin_amdgcn_global_load_lds((const __attribute__((address_space(1))) void*)g,
                                     (__attribute__((address_space(3))) void*)l, 16, 0, 0);
}

__device__ __forceinline__ float bf2f(unsigned short u) {
    union { unsigned i; float f; } v; v.i = ((unsigned)u) << 16; return v.f;
}

// ---------------------------------------------------------------------------
// padconv6: 6 fp32->bf16 zero-padded conversions in one launch.
// ---------------------------------------------------------------------------
struct PadJob {
    const float* src; unsigned short* dst;
    int src_ld, col0, M, K, Kp;
    int chunk_begin;
};
struct PadJobs { PadJob j[6]; int total; };

__global__ __launch_bounds__(256)
void padconv6(PadJobs P)
{
    const int idx = blockIdx.x * 256 + threadIdx.x;
    if (idx >= P.total) return;
    int ji = 0;
    #pragma unroll
    for (int k = 1; k < 6; ++k) if (idx >= P.j[k].chunk_begin) ji = k;
    const PadJob J = P.j[ji];
    const int cid = idx - J.chunk_begin;
    const int kp8 = J.Kp >> 3;
    const int m = cid / kp8;
    const int kc = (cid - m * kp8) << 3;
    u16x8 v;
    if (m < J.M && kc + 8 <= J.K) {
        const float* s = J.src + (size_t)m * J.src_ld + J.col0 + kc;
        const float4 f0 = *(const float4*)s;
        const float4 f1 = *(const float4*)(s + 4);
        const float ff[8] = {f0.x, f0.y, f0.z, f0.w, f1.x, f1.y, f1.z, f1.w};
        #pragma unroll
        for (int j = 0; j < 8; ++j) {
            __hip_bfloat16 h = __float2bfloat16(ff[j]);
            v[j] = *(unsigned short*)&h;
        }
    } else {
        #pragma unroll
        for (int j = 0; j < 8; ++j) {
            float f = 0.f;
            const int k = kc + j;
            if (m < J.M && k < J.K) f = J.src[(size_t)m * J.src_ld + J.col0 + k];
            __hip_bfloat16 h = __float2bfloat16(f);
            v[j] = *(unsigned short*)&h;
        }
    }
    *(u16x8*)(J.dst + (size_t)m * J.Kp + kc) = v;
}

// ---------------------------------------------------------------------------
// MFMA GEMM (unchanged from round 2): tile 64x64, 4 waves, split-K via gridDim.z
// ---------------------------------------------------------------------------
template<bool RELU, bool BIAS, bool BF16OUT>
__global__ __launch_bounds__(256)
void gemm_mfma(const unsigned short* __restrict__ A,
               const unsigned short* __restrict__ B,
               const float* __restrict__ bias,
               void* __restrict__ Cout, int ldc,
               int Mtrue, int Ntrue, int Kp, int Kc)
{
    __shared__ short As[64 * 64];
    __shared__ short Bs[64 * 64];
    const int bm = blockIdx.y * 64, bn = blockIdx.x * 64;
    const int tid = threadIdx.x;
    const int w = tid >> 6, l = tid & 63;
    const int wm = w >> 1, wn = w & 1;
    const int k_begin = blockIdx.z * Kc;
    const int k_end   = (k_begin + Kc < Kp) ? k_begin + Kc : Kp;

    const int sr0 = w * 8 + (l >> 3);
    const int scb = (l & 7) * 16;

    f32x4 acc[2][2];
    #pragma unroll
    for (int i = 0; i < 2; ++i)
        #pragma unroll
        for (int j = 0; j < 2; ++j)
            acc[i][j] = (f32x4){0.f, 0.f, 0.f, 0.f};

    for (int k0 = k_begin; k0 < k_end; k0 += 64) {
        #pragma unroll
        for (int c = 0; c < 2; ++c) {
            const int r = c * 32 + sr0;
            const int cbs = scb ^ ((r & 7) << 4);
            const char* ga = (const char*)(A + (size_t)(bm + r) * Kp + k0) + cbs;
            const char* gb = (const char*)(B + (size_t)(bn + r) * Kp + k0) + cbs;
            char* la = (char*)As + (size_t)(c * 32 + w * 8) * 128;
            char* lb = (char*)Bs + (size_t)(c * 32 + w * 8) * 128;
            gload16(ga, la);
            gload16(gb, lb);
        }
        asm volatile("s_waitcnt vmcnt(0)");
        __syncthreads();

        #pragma unroll
        for (int ks = 0; ks < 64; ks += 32) {
            bf16x8 a[2], b[2];
            const int kb = ks * 2 + (l >> 4) * 16;
            #pragma unroll
            for (int i = 0; i < 2; ++i) {
                const int ra = wm * 32 + i * 16 + (l & 15);
                a[i] = *(const bf16x8*)((const char*)As + ra * 128 + (kb ^ ((ra & 7) << 4)));
                const int rb = wn * 32 + i * 16 + (l & 15);
                b[i] = *(const bf16x8*)((const char*)Bs + rb * 128 + (kb ^ ((rb & 7) << 4)));
            }
            #pragma unroll
            for (int i = 0; i < 2; ++i)
                #pragma unroll
                for (int j = 0; j < 2; ++j)
                    acc[i][j] = __builtin_amdgcn_mfma_f32_16x16x32_bf16(a[i], b[j], acc[i][j], 0, 0, 0);
        }
        __syncthreads();
    }

    #pragma unroll
    for (int i = 0; i < 2; ++i) {
        #pragma unroll
        for (int j = 0; j < 2; ++j) {
            const int col = bn + wn * 32 + j * 16 + (l & 15);
            float bv = 0.f;
            if (BIAS && col < Ntrue) bv = bias[col];
            #pragma unroll
            for (int q = 0; q < 4; ++q) {
                const int row = bm + wm * 32 + i * 16 + (l >> 4) * 4 + q;
                float v = acc[i][j][q] + bv;
                if (RELU) v = fmaxf(v, 0.f);
                if (BF16OUT) {
                    if (row >= Mtrue) v = 0.f;
                    __hip_bfloat16 h = __float2bfloat16(v);
                    ((unsigned short*)Cout)[(size_t)row * ldc + col] = *(unsigned short*)&h;
                } else {
                    if (row < Mtrue && col < Ntrue) {
                        float* Cf = (float*)Cout + (size_t)blockIdx.z * Mtrue * ldc;
                        Cf[(size_t)row * ldc + col] = v;
                    }
                }
            }
        }
    }
}

// ---------------------------------------------------------------------------
// reduce_slabs: sum fp32 split-K slabs [nslab][M][900] -> bf16 [M][904]
// (optional bias add), zero-padding cols 900..903.
// ---------------------------------------------------------------------------
template<bool BIAS>
__global__ __launch_bounds__(256)
void reduce_slabs(const float* __restrict__ p, const float* __restrict__ bias,
                  unsigned short* __restrict__ o, int M, int nslab)
{
    const int idx = blockIdx.x * 256 + threadIdx.x;
    const int m = idx / 113;
    if (m >= M) return;
    const int c = idx - m * 113;
    const int k = c * 8;
    u16x8 v;
    #pragma unroll
    for (int q = 0; q < 8; q += 4) {
        if (k + q < 900) {
            float4 a = *(const float4*)(p + (size_t)m * 900 + k + q);
            for (int s = 1; s < nslab; ++s) {
                const float4 t = *(const float4*)(p + ((size_t)s * M + m) * 900 + k + q);
                a.x += t.x; a.y += t.y; a.z += t.z; a.w += t.w;
            }
            if (BIAS) {
                const float4 bb = *(const float4*)(bias + k + q);
                a.x += bb.x; a.y += bb.y; a.z += bb.z; a.w += bb.w;
            }
            const float ff[4] = {a.x, a.y, a.z, a.w};
            #pragma unroll
            for (int j = 0; j < 4; ++j) {
                __hip_bfloat16 h = __float2bfloat16(ff[j]);
                v[q + j] = *(unsigned short*)&h;
            }
        } else {
            #pragma unroll
            for (int j = 0; j < 4; ++j) v[q + j] = 0;
        }
    }
    *(u16x8*)(o + (size_t)m * 904 + k) = v;
}

// ---------------------------------------------------------------------------
// score/loss: block = 512 thr = 4 hs x 8 si x 16 ni; grid = (4 nt, 16 st, 4 b)
// z[s][n] = sum_h relu(hxb[s][h] + ha[n][h]) * w4[h]  (b3 pre-folded into hxb)
// ---------------------------------------------------------------------------
__global__ __launch_bounds__(512)
void score_loss(const unsigned short* __restrict__ hxb,  // [512][904] bf16 (hx+b3)
                const unsigned short* __restrict__ hab,  // [200][904] bf16
                const float* __restrict__ W4,            // [900]
                const float* __restrict__ b4,
                const int* __restrict__ xl,              // [512]
                const int* __restrict__ al,              // [200]
                float* __restrict__ out)
{
    __shared__ __align__(16) unsigned short hxs[8 * 904];
    __shared__ __align__(16) unsigned short has[16 * 904];
    __shared__ __align__(16) float w4s[904];
    __shared__ float zpart[4][8][16];
    __shared__ float red[2];

    const int tid = threadIdx.x;
    const int nt = blockIdx.x, st = blockIdx.y, b = blockIdx.z;
    const int row0 = b * 128 + st * 8;       // first s-row (global)

    // ---- stage hx tile (8 rows), ha tile (16 rows), w4 ----
    for (int t = tid; t < 24 * 113; t += 512) {
        u16x8 v;
        unsigned short* dst;
        if (t < 8 * 113) {
            const int r = t / 113, c = t - r * 113;
            v = *(const u16x8*)(hxb + (size_t)(row0 + r) * 904 + c * 8);
            dst = hxs + r * 904 + c * 8;
        } else {
            const int t2 = t - 8 * 113;
            const int r = t2 / 113, c = t2 - r * 113;
            const int n = nt * 16 + r;
            if (n < 50) v = *(const u16x8*)(hab + (size_t)(b * 50 + n) * 904 + c * 8);
            else        v = (u16x8){0,0,0,0,0,0,0,0};
            dst = has + r * 904 + c * 8;
        }
        *(u16x8*)dst = v;
    }
    for (int t = tid; t < 226; t += 512) {
        float4 v;
        if (t < 225) v = *(const float4*)(W4 + t * 4);
        else { v.x = W4[900 - 4 + 0]; v.x = 0.f; v.y = 0.f; v.z = 0.f; v.w = 0.f; }
        *(float4*)(w4s + t * 4) = v;
    }
    __syncthreads();

    const int hs = tid >> 7;
    const int si = (tid >> 4) & 7;
    const int ni = tid & 15;

    // ---- main accumulation: h-chunks c = hs, hs+4, ... < 113 ----
    float acc = 0.f;
    const unsigned short* hrow = hxs + si * 904;
    const unsigned short* arow = has + ni * 904;
    for (int c = hs; c < 113; c += 4) {
        const u16x8 hv = *(const u16x8*)(hrow + c * 8);
        const u16x8 av = *(const u16x8*)(arow + c * 8);
        const float4 w0 = *(const float4*)(w4s + c * 8);
        const float4 w1 = *(const float4*)(w4s + c * 8 + 4);
        const float ww[8] = {w0.x, w0.y, w0.z, w0.w, w1.x, w1.y, w1.z, w1.w};
        #pragma unroll
        for (int j = 0; j < 8; ++j) {
            const float u = bf2f((unsigned short)hv[j]) + bf2f((unsigned short)av[j]);
            acc = fmaf(fmaxf(u, 0.f), ww[j], acc);
        }
    }
    zpart[hs][si][ni] = acc;
    __syncthreads();

    // ---- epilogue: 128 threads finish one (si,ni) each ----
    float dd = 0.f;
    if (tid < 128) {
        const int esi = tid >> 4, eni = tid & 15;
        const int n = nt * 16 + eni;
        const float z = zpart[0][esi][eni] + zpart[1][esi][eni]
                      + zpart[2][esi][eni] + zpart[3][esi][eni] + b4[0];
        const float sc = 1.f / (1.f + __expf(-z));
        if (n < 50) {
            const float lab = (xl[row0 + esi] == al[b * 50 + n]) ? 1.f : 0.f;
            const float d = lab - sc;
            dd = d * d;
        }
    }
    if (tid < 128) {
        #pragma unroll
        for (int off = 32; off > 0; off >>= 1)
            dd += __shfl_down(dd, off);
        if ((tid & 63) == 0) red[tid >> 6] = dd;
    }
    __syncthreads();
    if (tid == 0) atomicAdd(out, (red[0] + red[1]) * (1.f / 512.f));
}

extern "C" void kernel_launch(void* const* d_in, const int* in_sizes, int n_in,
                              void* d_out, int out_size, void* d_ws, size_t ws_size,
                              hipStream_t stream)
{
    const float* x   = (const float*)d_in[0];
    const int*   xl  = (const int*)  d_in[1];
    const float* att = (const float*)d_in[2];
    const int*   al  = (const int*)  d_in[3];
    const float* W1  = (const float*)d_in[4];
    const float* b1  = (const float*)d_in[5];
    const float* W2  = (const float*)d_in[6];
    const float* b2  = (const float*)d_in[7];
    const float* W3  = (const float*)d_in[8];
    const float* b3  = (const float*)d_in[9];
    const float* W4  = (const float*)d_in[10];
    const float* b4  = (const float*)d_in[11];
    float* out = (float*)d_out;

    const int B = 4, S = 128, N = 50, C = 4096, H = 900, AR = 312;
    const int MS = B * S;           // 512
    const int MN = B * N;           // 200
    const int MNp = 256;
    const int ARp = 320, Hp = 960;
    const int SPLITS = 8, KC = 512;

    char* base = (char*)d_ws;
    size_t off = 0;
    auto alloc = [&](size_t bytes) { void* r = base + off; off = (off + bytes + 255) & ~(size_t)255; return r; };
    unsigned short* x_bf   = (unsigned short*)alloc((size_t)MS * C * 2);
    unsigned short* att_bf = (unsigned short*)alloc((size_t)MNp * ARp * 2);
    unsigned short* W1_bf  = (unsigned short*)alloc((size_t)Hp * ARp * 2);
    unsigned short* W2_bf  = (unsigned short*)alloc((size_t)C * Hp * 2);
    unsigned short* W3x_bf = (unsigned short*)alloc((size_t)Hp * C * 2);
    unsigned short* W3a_bf = (unsigned short*)alloc((size_t)Hp * C * 2);
    unsigned short* h1_bf  = (unsigned short*)alloc((size_t)MNp * Hp * 2);
    unsigned short* attf_bf= (unsigned short*)alloc((size_t)MNp * C * 2);
    float* hxp = (float*)alloc((size_t)SPLITS * MS * H * 4);
    float* hap = (float*)alloc((size_t)SPLITS * MN * H * 4);
    unsigned short* hx_bf = (unsigned short*)alloc((size_t)MS * 904 * 2);
    unsigned short* ha_bf = (unsigned short*)alloc((size_t)MN * 904 * 2);

    hipMemsetAsync(d_out, 0, sizeof(float), stream);

    const dim3 blk(256);
    auto cdiv = [](int a, int b) { return (a + b - 1) / b; };

    // ---- fused bf16 conversions ----
    PadJobs P;
    int cb = 0;
    auto setjob = [&](int i, const float* src, unsigned short* dst, int ld, int col0,
                      int M, int K, int Kp, int Mp) {
        P.j[i] = PadJob{src, dst, ld, col0, M, K, Kp, cb};
        cb += Mp * (Kp >> 3);
    };
    setjob(0, x,   x_bf,   C,     0, MS, C,  C,   MS);
    setjob(1, att, att_bf, AR,    0, MN, AR, ARp, MNp);
    setjob(2, W1,  W1_bf,  AR,    0, H,  AR, ARp, Hp);
    setjob(3, W2,  W2_bf,  H,     0, C,  H,  Hp,  C);
    setjob(4, W3,  W3x_bf, 2 * C, 0, H,  C,  C,   Hp);
    setjob(5, W3,  W3a_bf, 2 * C, C, H,  C,  C,   Hp);
    P.total = cb;
    padconv6<<<cdiv(cb, 256), blk, 0, stream>>>(P);

    // ---- G1: h1 = relu(att @ W1^T + b1) ----
    gemm_mfma<true, true, true><<<dim3(Hp / 64, MNp / 64, 1), blk, 0, stream>>>(
        att_bf, W1_bf, b1, h1_bf, Hp, MN, H, ARp, ARp);

    // ---- G2: attf = relu(h1 @ W2^T + b2) ----
    gemm_mfma<true, true, true><<<dim3(C / 64, MNp / 64, 1), blk, 0, stream>>>(
        h1_bf, W2_bf, b2, attf_bf, C, MN, C, Hp, Hp);

    // ---- G3: hxp = x @ W3x^T (split-K 8) ----
    gemm_mfma<false, false, false><<<dim3(Hp / 64, MS / 64, SPLITS), blk, 0, stream>>>(
        x_bf, W3x_bf, nullptr, hxp, H, MS, H, C, KC);

    // ---- G4: hap = attf @ W3a^T (split-K 8) ----
    gemm_mfma<false, false, false><<<dim3(Hp / 64, MNp / 64, SPLITS), blk, 0, stream>>>(
        attf_bf, W3a_bf, nullptr, hap, H, MN, H, C, KC);

    // ---- reduce slabs -> bf16 (b3 folded into hx) ----
    reduce_slabs<true><<<cdiv(MS * 113, 256), blk, 0, stream>>>(hxp, b3, hx_bf, MS, SPLITS);
    reduce_slabs<false><<<cdiv(MN * 113, 256), blk, 0, stream>>>(hap, nullptr, ha_bf, MN, SPLITS);

    // ---- score + loss ----
    score_loss<<<dim3(4, 16, 4), dim3(512), 0, stream>>>(hx_bf, ha_bf, W4, b4, xl, al, out);
}

// Round 4
// 71.243 us; speedup vs baseline: 17.1039x; 1.2833x over previous
//
#include <hip/hip_runtime.h>
#include <hip/hip_bf16.h>

typedef __attribute__((ext_vector_type(8))) short bf16x8;
typedef __attribute__((ext_vector_type(4))) float f32x4;
typedef __attribute__((ext_vector_type(8))) unsigned short u16x8;

__device__ __forceinline__ void gload16(const void* g, void* l) {
    __builtin_amdgcn_global_load_lds((const __attribute__((address_space(1))) void*)g,
                                     (__attribute__((address_space(3))) void*)l, 16, 0, 0);
}

__device__ __forceinline__ float bf2f(unsigned short u) {
    union { unsigned i; float f; } v; v.i = ((unsigned)u) << 16; return v.f;
}

// ---------------------------------------------------------------------------
// padconv6: 6 fp32->bf16 zero-padded conversions in one launch.
// ---------------------------------------------------------------------------
struct PadJob {
    const float* src; unsigned short* dst;
    int src_ld, col0, M, K, Kp;
    int chunk_begin;
};
struct PadJobs { PadJob j[6]; int total; };

__global__ __launch_bounds__(256)
void padconv6(PadJobs P)
{
    const int idx = blockIdx.x * 256 + threadIdx.x;
    if (idx >= P.total) return;
    int ji = 0;
    #pragma unroll
    for (int k = 1; k < 6; ++k) if (idx >= P.j[k].chunk_begin) ji = k;
    const PadJob J = P.j[ji];
    const int cid = idx - J.chunk_begin;
    const int kp8 = J.Kp >> 3;
    const int m = cid / kp8;
    const int kc = (cid - m * kp8) << 3;
    u16x8 v;
    if (m < J.M && kc + 8 <= J.K) {
        const float* s = J.src + (size_t)m * J.src_ld + J.col0 + kc;
        const float4 f0 = *(const float4*)s;
        const float4 f1 = *(const float4*)(s + 4);
        const float ff[8] = {f0.x, f0.y, f0.z, f0.w, f1.x, f1.y, f1.z, f1.w};
        #pragma unroll
        for (int j = 0; j < 8; ++j) {
            __hip_bfloat16 h = __float2bfloat16(ff[j]);
            v[j] = *(unsigned short*)&h;
        }
    } else {
        #pragma unroll
        for (int j = 0; j < 8; ++j) {
            float f = 0.f;
            const int k = kc + j;
            if (m < J.M && k < J.K) f = J.src[(size_t)m * J.src_ld + J.col0 + k];
            __hip_bfloat16 h = __float2bfloat16(f);
            v[j] = *(unsigned short*)&h;
        }
    }
    *(u16x8*)(J.dst + (size_t)m * J.Kp + kc) = v;
}

// ---------------------------------------------------------------------------
// 64x64-tile MFMA GEMM (G1/G2): C = act(A@B^T + bias), bf16 out, padded rows zeroed
// ---------------------------------------------------------------------------
template<bool RELU, bool BIAS>
__global__ __launch_bounds__(256)
void gemm_mfma64(const unsigned short* __restrict__ A,
                 const unsigned short* __restrict__ B,
                 const float* __restrict__ bias,
                 unsigned short* __restrict__ Cout, int ldc,
                 int Mtrue, int Ntrue, int Kp)
{
    __shared__ short As[64 * 64];
    __shared__ short Bs[64 * 64];
    const int bm = blockIdx.y * 64, bn = blockIdx.x * 64;
    const int tid = threadIdx.x;
    const int w = tid >> 6, l = tid & 63;
    const int wm = w >> 1, wn = w & 1;

    const int sr0 = w * 8 + (l >> 3);
    const int scb = (l & 7) * 16;

    f32x4 acc[2][2];
    #pragma unroll
    for (int i = 0; i < 2; ++i)
        #pragma unroll
        for (int j = 0; j < 2; ++j)
            acc[i][j] = (f32x4){0.f, 0.f, 0.f, 0.f};

    for (int k0 = 0; k0 < Kp; k0 += 64) {
        #pragma unroll
        for (int c = 0; c < 2; ++c) {
            const int r = c * 32 + sr0;
            const int cbs = scb ^ ((r & 7) << 4);
            const char* ga = (const char*)(A + (size_t)(bm + r) * Kp + k0) + cbs;
            const char* gb = (const char*)(B + (size_t)(bn + r) * Kp + k0) + cbs;
            char* la = (char*)As + (size_t)(c * 32 + w * 8) * 128;
            char* lb = (char*)Bs + (size_t)(c * 32 + w * 8) * 128;
            gload16(ga, la);
            gload16(gb, lb);
        }
        asm volatile("s_waitcnt vmcnt(0)");
        __syncthreads();

        #pragma unroll
        for (int ks = 0; ks < 64; ks += 32) {
            bf16x8 a[2], b[2];
            const int kb = ks * 2 + (l >> 4) * 16;
            #pragma unroll
            for (int i = 0; i < 2; ++i) {
                const int ra = wm * 32 + i * 16 + (l & 15);
                a[i] = *(const bf16x8*)((const char*)As + ra * 128 + (kb ^ ((ra & 7) << 4)));
                const int rb = wn * 32 + i * 16 + (l & 15);
                b[i] = *(const bf16x8*)((const char*)Bs + rb * 128 + (kb ^ ((rb & 7) << 4)));
            }
            #pragma unroll
            for (int i = 0; i < 2; ++i)
                #pragma unroll
                for (int j = 0; j < 2; ++j)
                    acc[i][j] = __builtin_amdgcn_mfma_f32_16x16x32_bf16(a[i], b[j], acc[i][j], 0, 0, 0);
        }
        __syncthreads();
    }

    #pragma unroll
    for (int i = 0; i < 2; ++i) {
        #pragma unroll
        for (int j = 0; j < 2; ++j) {
            const int col = bn + wn * 32 + j * 16 + (l & 15);
            float bv = 0.f;
            if (BIAS && col < Ntrue) bv = bias[col];
            #pragma unroll
            for (int q = 0; q < 4; ++q) {
                const int row = bm + wm * 32 + i * 16 + (l >> 4) * 4 + q;
                float v = acc[i][j][q] + bv;
                if (RELU) v = fmaxf(v, 0.f);
                if (row >= Mtrue) v = 0.f;
                __hip_bfloat16 h = __float2bfloat16(v);
                Cout[(size_t)row * ldc + col] = *(unsigned short*)&h;
            }
        }
    }
}

// ---------------------------------------------------------------------------
// 128x128-tile split-K GEMM for G3+G4 fused in one launch.
// blocks [0,256): G3  z=gid>>5, by=(gid&31)>>3 (0..3), bx=gid&7
// blocks [256,384): G4 z=g>>4,  by=(g&15)>>3 (0..1),  bx=g&7
// A [Mp][4096] bf16, B [1024][4096] bf16; partial fp32 slab [z][Mtrue][900].
// ---------------------------------------------------------------------------
struct G34Args {
    const unsigned short *A3, *B3; float* P3;
    const unsigned short *A4, *B4; float* P4;
};

__global__ __launch_bounds__(256)
void gemm128_split(G34Args ga)
{
    __shared__ short As[128 * 64];
    __shared__ short Bs[128 * 64];
    const int tid = threadIdx.x;
    const int w = tid >> 6, l = tid & 63;
    const int wm = w >> 1, wn = w & 1;

    const unsigned short *A, *Bm;
    float* P;
    int by, bx, z, Mtrue;
    const int gid = blockIdx.x;
    if (gid < 256) {
        z = gid >> 5; const int rem = gid & 31; by = rem >> 3; bx = rem & 7;
        A = ga.A3; Bm = ga.B3; P = ga.P3; Mtrue = 512;
    } else {
        const int g2 = gid - 256;
        z = g2 >> 4; const int rem = g2 & 15; by = rem >> 3; bx = rem & 7;
        A = ga.A4; Bm = ga.B4; P = ga.P4; Mtrue = 200;
    }
    const int Kp = 4096;
    const int k_begin = z * 512;

    const int sr0 = w * 8 + (l >> 3);       // 0..31 within each 32-row chunk
    const int scb = (l & 7) * 16;
    const int swa = scb ^ ((sr0 & 7) << 4); // source byte col, XOR-swizzled

    f32x4 acc[4][4];
    #pragma unroll
    for (int i = 0; i < 4; ++i)
        #pragma unroll
        for (int j = 0; j < 4; ++j)
            acc[i][j] = (f32x4){0.f, 0.f, 0.f, 0.f};

    for (int k0 = k_begin; k0 < k_begin + 512; k0 += 64) {
        #pragma unroll
        for (int c = 0; c < 4; ++c) {
            const int r = c * 32 + sr0;
            const char* gA = (const char*)(A  + (size_t)(by * 128 + r) * Kp + k0) + swa;
            const char* gB = (const char*)(Bm + (size_t)(bx * 128 + r) * Kp + k0) + swa;
            char* la = (char*)As + (size_t)(c * 32 + w * 8) * 128;
            char* lb = (char*)Bs + (size_t)(c * 32 + w * 8) * 128;
            gload16(gA, la);
            gload16(gB, lb);
        }
        asm volatile("s_waitcnt vmcnt(0)");
        __syncthreads();

        #pragma unroll
        for (int ks = 0; ks < 64; ks += 32) {
            bf16x8 a[4], b[4];
            const int kb = ks * 2 + (l >> 4) * 16;
            #pragma unroll
            for (int i = 0; i < 4; ++i) {
                const int ra = wm * 64 + i * 16 + (l & 15);
                a[i] = *(const bf16x8*)((const char*)As + ra * 128 + (kb ^ ((ra & 7) << 4)));
                const int rb = wn * 64 + i * 16 + (l & 15);
                b[i] = *(const bf16x8*)((const char*)Bs + rb * 128 + (kb ^ ((rb & 7) << 4)));
            }
            #pragma unroll
            for (int i = 0; i < 4; ++i)
                #pragma unroll
                for (int j = 0; j < 4; ++j)
                    acc[i][j] = __builtin_amdgcn_mfma_f32_16x16x32_bf16(a[i], b[j], acc[i][j], 0, 0, 0);
        }
        __syncthreads();
    }

    float* slab = P + (size_t)z * Mtrue * 900;
    #pragma unroll
    for (int i = 0; i < 4; ++i) {
        #pragma unroll
        for (int j = 0; j < 4; ++j) {
            const int col = bx * 128 + wn * 64 + j * 16 + (l & 15);
            if (col >= 900) continue;
            #pragma unroll
            for (int q = 0; q < 4; ++q) {
                const int row = by * 128 + wm * 64 + i * 16 + (l >> 4) * 4 + q;
                if (row < Mtrue)
                    slab[(size_t)row * 900 + col] = acc[i][j][q];
            }
        }
    }
}

// ---------------------------------------------------------------------------
// reduce_both: sum split-K slabs for hx (with b3) and ha -> bf16 [M][904]
// ---------------------------------------------------------------------------
__global__ __launch_bounds__(256)
void reduce_both(const float* __restrict__ hxp, const float* __restrict__ hap,
                 const float* __restrict__ b3,
                 unsigned short* __restrict__ hx_bf, unsigned short* __restrict__ ha_bf)
{
    int idx = blockIdx.x * 256 + threadIdx.x;
    const int HX = 512 * 113;
    const float* p; unsigned short* o; const float* bias; int M, m;
    if (idx < HX) { p = hxp; o = hx_bf; bias = b3; M = 512; }
    else {
        idx -= HX;
        if (idx >= 200 * 113) return;
        p = hap; o = ha_bf; bias = nullptr; M = 200;
    }
    m = idx / 113;
    const int c = idx - m * 113;
    const int k = c * 8;
    u16x8 v;
    #pragma unroll
    for (int q = 0; q < 8; q += 4) {
        if (k + q < 900) {
            float4 a = *(const float4*)(p + (size_t)m * 900 + k + q);
            #pragma unroll 1
            for (int s = 1; s < 8; ++s) {
                const float4 t = *(const float4*)(p + ((size_t)s * M + m) * 900 + k + q);
                a.x += t.x; a.y += t.y; a.z += t.z; a.w += t.w;
            }
            if (bias) {
                const float4 bb = *(const float4*)(bias + k + q);
                a.x += bb.x; a.y += bb.y; a.z += bb.z; a.w += bb.w;
            }
            const float ff[4] = {a.x, a.y, a.z, a.w};
            #pragma unroll
            for (int j = 0; j < 4; ++j) {
                __hip_bfloat16 h = __float2bfloat16(ff[j]);
                v[q + j] = *(unsigned short*)&h;
            }
        } else {
            #pragma unroll
            for (int j = 0; j < 4; ++j) v[q + j] = 0;
        }
    }
    *(u16x8*)(o + (size_t)m * 904 + k) = v;
}

// ---------------------------------------------------------------------------
// score/loss: block = 512 thr = 4 hs x 8 si x 16 ni; grid = (4 nt, 16 st, 4 b)
// writes per-block partial sum of d^2 to part[].
// ---------------------------------------------------------------------------
__global__ __launch_bounds__(512)
void score_loss(const unsigned short* __restrict__ hxb,
                const unsigned short* __restrict__ hab,
                const float* __restrict__ W4,
                const float* __restrict__ b4,
                const int* __restrict__ xl,
                const int* __restrict__ al,
                float* __restrict__ part)
{
    __shared__ __align__(16) unsigned short hxs[8 * 904];
    __shared__ __align__(16) unsigned short has[16 * 904];
    __shared__ __align__(16) float w4s[904];
    __shared__ float zpart[4][8][16];
    __shared__ float red[2];

    const int tid = threadIdx.x;
    const int nt = blockIdx.x, st = blockIdx.y, b = blockIdx.z;
    const int row0 = b * 128 + st * 8;

    for (int t = tid; t < 24 * 113; t += 512) {
        u16x8 v;
        unsigned short* dst;
        if (t < 8 * 113) {
            const int r = t / 113, c = t - r * 113;
            v = *(const u16x8*)(hxb + (size_t)(row0 + r) * 904 + c * 8);
            dst = hxs + r * 904 + c * 8;
        } else {
            const int t2 = t - 8 * 113;
            const int r = t2 / 113, c = t2 - r * 113;
            const int n = nt * 16 + r;
            if (n < 50) v = *(const u16x8*)(hab + (size_t)(b * 50 + n) * 904 + c * 8);
            else        v = (u16x8){0,0,0,0,0,0,0,0};
            dst = has + r * 904 + c * 8;
        }
        *(u16x8*)dst = v;
    }
    for (int t = tid; t < 226; t += 512) {
        float4 v = {0.f, 0.f, 0.f, 0.f};
        if (t < 225) v = *(const float4*)(W4 + t * 4);
        *(float4*)(w4s + t * 4) = v;
    }
    __syncthreads();

    const int hs = tid >> 7;
    const int si = (tid >> 4) & 7;
    const int ni = tid & 15;

    float acc = 0.f;
    const unsigned short* hrow = hxs + si * 904;
    const unsigned short* arow = has + ni * 904;
    for (int c = hs; c < 113; c += 4) {
        const u16x8 hv = *(const u16x8*)(hrow + c * 8);
        const u16x8 av = *(const u16x8*)(arow + c * 8);
        const float4 w0 = *(const float4*)(w4s + c * 8);
        const float4 w1 = *(const float4*)(w4s + c * 8 + 4);
        const float ww[8] = {w0.x, w0.y, w0.z, w0.w, w1.x, w1.y, w1.z, w1.w};
        #pragma unroll
        for (int j = 0; j < 8; ++j) {
            const float u = bf2f((unsigned short)hv[j]) + bf2f((unsigned short)av[j]);
            acc = fmaf(fmaxf(u, 0.f), ww[j], acc);
        }
    }
    zpart[hs][si][ni] = acc;
    __syncthreads();

    float dd = 0.f;
    if (tid < 128) {
        const int esi = tid >> 4, eni = tid & 15;
        const int n = nt * 16 + eni;
        const float z = zpart[0][esi][eni] + zpart[1][esi][eni]
                      + zpart[2][esi][eni] + zpart[3][esi][eni] + b4[0];
        const float sc = 1.f / (1.f + __expf(-z));
        if (n < 50) {
            const float lab = (xl[row0 + esi] == al[b * 50 + n]) ? 1.f : 0.f;
            const float d = lab - sc;
            dd = d * d;
        }
        #pragma unroll
        for (int off = 32; off > 0; off >>= 1)
            dd += __shfl_down(dd, off);
        if ((tid & 63) == 0) red[tid >> 6] = dd;
    }
    __syncthreads();
    if (tid == 0)
        part[nt + 4 * (st + 16 * b)] = red[0] + red[1];
}

// Sum 256 block partials -> loss
__global__ __launch_bounds__(256)
void final_loss(const float* __restrict__ part, float* __restrict__ out)
{
    __shared__ float r[4];
    const int tid = threadIdx.x;
    float v = part[tid];
    #pragma unroll
    for (int off = 32; off > 0; off >>= 1)
        v += __shfl_down(v, off);
    if ((tid & 63) == 0) r[tid >> 6] = v;
    __syncthreads();
    if (tid == 0) out[0] = (r[0] + r[1] + r[2] + r[3]) * (1.f / 512.f);
}

extern "C" void kernel_launch(void* const* d_in, const int* in_sizes, int n_in,
                              void* d_out, int out_size, void* d_ws, size_t ws_size,
                              hipStream_t stream)
{
    const float* x   = (const float*)d_in[0];
    const int*   xl  = (const int*)  d_in[1];
    const float* att = (const float*)d_in[2];
    const int*   al  = (const int*)  d_in[3];
    const float* W1  = (const float*)d_in[4];
    const float* b1  = (const float*)d_in[5];
    const float* W2  = (const float*)d_in[6];
    const float* b2  = (const float*)d_in[7];
    const float* W3  = (const float*)d_in[8];
    const float* b3  = (const float*)d_in[9];
    const float* W4  = (const float*)d_in[10];
    const float* b4  = (const float*)d_in[11];
    float* out = (float*)d_out;

    const int B = 4, S = 128, N = 50, C = 4096, H = 900, AR = 312;
    const int MS = B * S;            // 512
    const int MN = B * N;            // 200
    const int MNp = 256;
    const int ARp = 320, Hp = 960;   // G1/G2 padded dims
    const int W3p = 1024;            // W3 panel rows padded to 128-mult
    const int SPLITS = 8;

    char* base = (char*)d_ws;
    size_t off = 0;
    auto alloc = [&](size_t bytes) { void* r = base + off; off = (off + bytes + 255) & ~(size_t)255; return r; };
    unsigned short* x_bf   = (unsigned short*)alloc((size_t)MS * C * 2);
    unsigned short* att_bf = (unsigned short*)alloc((size_t)MNp * ARp * 2);
    unsigned short* W1_bf  = (unsigned short*)alloc((size_t)Hp * ARp * 2);
    unsigned short* W2_bf  = (unsigned short*)alloc((size_t)C * Hp * 2);
    unsigned short* W3x_bf = (unsigned short*)alloc((size_t)W3p * C * 2);
    unsigned short* W3a_bf = (unsigned short*)alloc((size_t)W3p * C * 2);
    unsigned short* h1_bf  = (unsigned short*)alloc((size_t)MNp * Hp * 2);
    unsigned short* attf_bf= (unsigned short*)alloc((size_t)MNp * C * 2);
    float* hxp = (float*)alloc((size_t)SPLITS * MS * H * 4);
    float* hap = (float*)alloc((size_t)SPLITS * MN * H * 4);
    unsigned short* hx_bf = (unsigned short*)alloc((size_t)MS * 904 * 2);
    unsigned short* ha_bf = (unsigned short*)alloc((size_t)MN * 904 * 2);
    float* part = (float*)alloc(256 * 4);

    const dim3 blk(256);
    auto cdiv = [](int a, int b) { return (a + b - 1) / b; };

    // ---- fused bf16 conversions ----
    PadJobs P;
    int cb = 0;
    auto setjob = [&](int i, const float* src, unsigned short* dst, int ld, int col0,
                      int M, int K, int Kp, int Mp) {
        P.j[i] = PadJob{src, dst, ld, col0, M, K, Kp, cb};
        cb += Mp * (Kp >> 3);
    };
    setjob(0, x,   x_bf,   C,     0, MS, C,  C,   MS);
    setjob(1, att, att_bf, AR,    0, MN, AR, ARp, MNp);
    setjob(2, W1,  W1_bf,  AR,    0, H,  AR, ARp, Hp);
    setjob(3, W2,  W2_bf,  H,     0, C,  H,  Hp,  C);
    setjob(4, W3,  W3x_bf, 2 * C, 0, H,  C,  C,   W3p);
    setjob(5, W3,  W3a_bf, 2 * C, C, H,  C,  C,   W3p);
    P.total = cb;
    padconv6<<<cdiv(cb, 256), blk, 0, stream>>>(P);

    // ---- G1: h1 = relu(att @ W1^T + b1)  [256][960], K=320 ----
    gemm_mfma64<true, true><<<dim3(Hp / 64, MNp / 64), blk, 0, stream>>>(
        att_bf, W1_bf, b1, h1_bf, Hp, MN, H, ARp);

    // ---- G2: attf = relu(h1 @ W2^T + b2) [256][4096], K=960 ----
    gemm_mfma64<true, true><<<dim3(C / 64, MNp / 64), blk, 0, stream>>>(
        h1_bf, W2_bf, b2, attf_bf, C, MN, C, Hp);

    // ---- G3+G4 fused: split-K 8, 128^2 tiles ----
    G34Args ga{x_bf, W3x_bf, hxp, attf_bf, W3a_bf, hap};
    gemm128_split<<<dim3(384), blk, 0, stream>>>(ga);

    // ---- reduce slabs -> bf16 (b3 folded into hx) ----
    reduce_both<<<cdiv((MS + MN) * 113, 256), blk, 0, stream>>>(hxp, hap, b3, hx_bf, ha_bf);

    // ---- score + loss ----
    score_loss<<<dim3(4, 16, 4), dim3(512), 0, stream>>>(hx_bf, ha_bf, W4, b4, xl, al, part);
    final_loss<<<dim3(1), blk, 0, stream>>>(part, out);
}